// Round 13
// baseline (132.601 us; speedup 1.0000x reference)
//
#include <hip/hip_runtime.h>

#define NE 8
#define DIM 1024
#define ALPHA_C 10.0f

typedef float f32x4 __attribute__((ext_vector_type(4)));

// 16 lanes per row, 4 rows per wave; 256-B visits (measured optimum).
// NT loads, W in LDS broadcast reads, implicit unroll-8 scheduling.
// R13 single variable: grid 1024 -> 512 (16 waves/CU, 16384 concurrent
// row-streams chip-wide instead of 32768) to probe DRAM bank-thrash.
__global__ __launch_bounds__(512, 8) void topk_gating_kernel(
    const float* __restrict__ x,
    const float* __restrict__ gw,
    const float* __restrict__ gb,
    float* __restrict__ out,
    int nrows)
{
    __shared__ float wlds[NE * DIM];   // 32 KiB

    const int tid = threadIdx.x;

    // Stage W into LDS, coalesced: 2048 float4 / 512 thr = 4 each
    {
        const float4* src = (const float4*)gw;
        float4* dst = (float4*)wlds;
        #pragma unroll
        for (int i = 0; i < 4; ++i)
            dst[tid + i * 512] = src[tid + i * 512];
    }
    float bias[NE];
    #pragma unroll
    for (int e = 0; e < NE; ++e) bias[e] = gb[e];
    __syncthreads();

    const int lane = tid & 63;
    const int g = lane >> 4;          // row-within-group-of-4
    const int s = lane & 15;          // sub-lane within row (16-B chunk index)
    const int wid = (blockIdx.x * blockDim.x + tid) >> 6;
    const int nwaves = (gridDim.x * blockDim.x) >> 6;

    const f32x4* x4 = (const f32x4*)x;
    const f32x4* w4 = (const f32x4*)wlds;

    for (int base = wid * 4; base < nrows; base += nwaves * 4) {
        const int row = base + g;
        const bool valid = row < nrows;
        const size_t xoff = (size_t)row * (DIM / 4) + s;

        float acc[NE] = {0.f, 0.f, 0.f, 0.f, 0.f, 0.f, 0.f, 0.f};
        if (valid) {
            // 16 j-steps; each wave-instruction reads 4 rows x 256 B
            #pragma unroll 8
            for (int j = 0; j < 16; ++j) {
                f32x4 xv = __builtin_nontemporal_load(&x4[xoff + (size_t)j * 16]);
                #pragma unroll
                for (int e = 0; e < NE; ++e) {
                    // 16 unique LDS addresses per wave instr -> cheap broadcast
                    f32x4 wv = w4[e * (DIM / 4) + j * 16 + s];
                    acc[e] += xv.x * wv.x + xv.y * wv.y + xv.z * wv.z + xv.w * wv.w;
                }
            }
        }

        // Allgather butterfly over the 16 lanes of each row: one shuffle
        // instruction reduces all 4 rows of the wave in parallel.
        #pragma unroll
        for (int e = 0; e < NE; ++e) {
            float v = acc[e];
            v += __shfl_xor(v, 1);
            v += __shfl_xor(v, 2);
            v += __shfl_xor(v, 4);
            v += __shfl_xor(v, 8);
            acc[e] = v + bias[e];
        }

        // ---- epilogue (redundant across the 16 lanes of a row) ----
        // max and 2nd-largest (duplicate-preserving == kthvalue semantics)
        float m1 = -INFINITY, m2 = -INFINITY;
        #pragma unroll
        for (int e = 0; e < NE; ++e) {
            float v = acc[e];
            float nm2 = fmaxf(m2, fminf(m1, v));
            m1 = fmaxf(m1, v);
            m2 = nm2;
        }

        // softmax of raw logits
        float ex[NE];
        float sum = 0.f;
        #pragma unroll
        for (int e = 0; e < NE; ++e) {
            ex[e] = __expf(acc[e] - m1);
            sum += ex[e];
        }
        float inv = 1.f / sum;

        // decomposition: (l < kth) -> ALPHA*log1p(s), else ALPHA*(exp(s)-1)
        float o[NE];
        #pragma unroll
        for (int e = 0; e < NE; ++e) {
            float sft = ex[e] * inv;
            float topv = ALPHA_C * (__expf(sft) - 1.f);
            float lowv = ALPHA_C * __logf(1.f + sft);
            o[e] = (acc[e] >= m2) ? topv : lowv;
        }

        // final softmax
        float om = o[0];
        #pragma unroll
        for (int e = 1; e < NE; ++e) om = fmaxf(om, o[e]);
        float oex[NE];
        float osum = 0.f;
        #pragma unroll
        for (int e = 0; e < NE; ++e) {
            oex[e] = __expf(o[e] - om);
            osum += oex[e];
        }
        float oinv = 1.f / osum;

        // lanes s<8 write gates[s]; per wave the 4 rows' stores form one
        // contiguous 128-B line. Compile-time-index select chain (no scratch).
        float gsel = oex[0] * oinv;
        #pragma unroll
        for (int e = 1; e < NE; ++e) {
            float ge = oex[e] * oinv;
            gsel = (s == e) ? ge : gsel;
        }
        if (valid && s < NE)
            __builtin_nontemporal_store(gsel, &out[(size_t)row * NE + s]);
    }
}

extern "C" void kernel_launch(void* const* d_in, const int* in_sizes, int n_in,
                              void* d_out, int out_size, void* d_ws, size_t ws_size,
                              hipStream_t stream) {
    const float* x  = (const float*)d_in[0];
    const float* gw = (const float*)d_in[1];
    const float* gb = (const float*)d_in[2];
    float* out = (float*)d_out;
    const int nrows = in_sizes[0] / DIM;

    const int block = 512;   // 8 waves/block, 32 KiB LDS
    const int grid = 512;    // 2 blocks/CU -> 16 waves/CU, half the streams
    topk_gating_kernel<<<grid, block, 0, stream>>>(x, gw, gb, out, nrows);
}

// Round 14
// 109.256 us; speedup vs baseline: 1.2137x; 1.2137x over previous
//
#include <hip/hip_runtime.h>

#define NE 8
#define DIM 1024
#define ALPHA_C 10.0f

typedef float f32x4 __attribute__((ext_vector_type(4)));

// FINAL (measured optimum, 109.5 us = 4.93 TB/s pure-read):
// 16 lanes per row, 4 rows per wave; 256-B visits per row per wave-instr
// (granularity ladder optimum: 64B->3.4, 128B->4.5, 256B->4.93 TB/s,
// 512B regresses). NT loads (no cache allocation, +5%), W in LDS with
// 16-unique-address broadcast reads (conflict-benign), implicit unroll-8
// scheduling (explicit load buffers spill at the 8-wave VGPR clamp -- R9).
// 512-thr blocks, grid=1024 = exactly 4 blocks/CU resident -> 32 waves/CU,
// zero dispatch tail (R13 probe: halving streams regresses to 132 us).
__global__ __launch_bounds__(512, 8) void topk_gating_kernel(
    const float* __restrict__ x,
    const float* __restrict__ gw,
    const float* __restrict__ gb,
    float* __restrict__ out,
    int nrows)
{
    __shared__ float wlds[NE * DIM];   // 32 KiB

    const int tid = threadIdx.x;

    // Stage W into LDS, coalesced: 2048 float4 / 512 thr = 4 each
    {
        const float4* src = (const float4*)gw;
        float4* dst = (float4*)wlds;
        #pragma unroll
        for (int i = 0; i < 4; ++i)
            dst[tid + i * 512] = src[tid + i * 512];
    }
    float bias[NE];
    #pragma unroll
    for (int e = 0; e < NE; ++e) bias[e] = gb[e];
    __syncthreads();

    const int lane = tid & 63;
    const int g = lane >> 4;          // row-within-group-of-4
    const int s = lane & 15;          // sub-lane within row (16-B chunk index)
    const int wid = (blockIdx.x * blockDim.x + tid) >> 6;
    const int nwaves = (gridDim.x * blockDim.x) >> 6;

    const f32x4* x4 = (const f32x4*)x;
    const f32x4* w4 = (const f32x4*)wlds;

    for (int base = wid * 4; base < nrows; base += nwaves * 4) {
        const int row = base + g;
        const bool valid = row < nrows;
        const size_t xoff = (size_t)row * (DIM / 4) + s;

        float acc[NE] = {0.f, 0.f, 0.f, 0.f, 0.f, 0.f, 0.f, 0.f};
        if (valid) {
            // 16 j-steps; each wave-instruction reads 4 rows x 256 B
            #pragma unroll 8
            for (int j = 0; j < 16; ++j) {
                f32x4 xv = __builtin_nontemporal_load(&x4[xoff + (size_t)j * 16]);
                #pragma unroll
                for (int e = 0; e < NE; ++e) {
                    // 16 unique LDS addresses per wave instr -> cheap broadcast
                    f32x4 wv = w4[e * (DIM / 4) + j * 16 + s];
                    acc[e] += xv.x * wv.x + xv.y * wv.y + xv.z * wv.z + xv.w * wv.w;
                }
            }
        }

        // Allgather butterfly over the 16 lanes of each row: one shuffle
        // instruction reduces all 4 rows of the wave in parallel.
        #pragma unroll
        for (int e = 0; e < NE; ++e) {
            float v = acc[e];
            v += __shfl_xor(v, 1);
            v += __shfl_xor(v, 2);
            v += __shfl_xor(v, 4);
            v += __shfl_xor(v, 8);
            acc[e] = v + bias[e];
        }

        // ---- epilogue (redundant across the 16 lanes of a row) ----
        // max and 2nd-largest (duplicate-preserving == kthvalue semantics)
        float m1 = -INFINITY, m2 = -INFINITY;
        #pragma unroll
        for (int e = 0; e < NE; ++e) {
            float v = acc[e];
            float nm2 = fmaxf(m2, fminf(m1, v));
            m1 = fmaxf(m1, v);
            m2 = nm2;
        }

        // softmax of raw logits
        float ex[NE];
        float sum = 0.f;
        #pragma unroll
        for (int e = 0; e < NE; ++e) {
            ex[e] = __expf(acc[e] - m1);
            sum += ex[e];
        }
        float inv = 1.f / sum;

        // decomposition: (l < kth) -> ALPHA*log1p(s), else ALPHA*(exp(s)-1)
        float o[NE];
        #pragma unroll
        for (int e = 0; e < NE; ++e) {
            float sft = ex[e] * inv;
            float topv = ALPHA_C * (__expf(sft) - 1.f);
            float lowv = ALPHA_C * __logf(1.f + sft);
            o[e] = (acc[e] >= m2) ? topv : lowv;
        }

        // final softmax
        float om = o[0];
        #pragma unroll
        for (int e = 1; e < NE; ++e) om = fmaxf(om, o[e]);
        float oex[NE];
        float osum = 0.f;
        #pragma unroll
        for (int e = 0; e < NE; ++e) {
            oex[e] = __expf(o[e] - om);
            osum += oex[e];
        }
        float oinv = 1.f / osum;

        // lanes s<8 write gates[s]; per wave the 4 rows' stores form one
        // contiguous 128-B line. Compile-time-index select chain (no scratch).
        float gsel = oex[0] * oinv;
        #pragma unroll
        for (int e = 1; e < NE; ++e) {
            float ge = oex[e] * oinv;
            gsel = (s == e) ? ge : gsel;
        }
        if (valid && s < NE)
            __builtin_nontemporal_store(gsel, &out[(size_t)row * NE + s]);
    }
}

extern "C" void kernel_launch(void* const* d_in, const int* in_sizes, int n_in,
                              void* d_out, int out_size, void* d_ws, size_t ws_size,
                              hipStream_t stream) {
    const float* x  = (const float*)d_in[0];
    const float* gw = (const float*)d_in[1];
    const float* gb = (const float*)d_in[2];
    float* out = (float*)d_out;
    const int nrows = in_sizes[0] / DIM;

    const int block = 512;   // 8 waves/block, 32 KiB LDS; 4 blocks/CU resident
    const int grid = 1024;   // exactly 4/CU -> 32 waves/CU, zero dispatch tail
    topk_gating_kernel<<<grid, block, 0, stream>>>(x, gw, gb, out, nrows);
}